// Round 5
// baseline (253.738 us; speedup 1.0000x reference)
//
#include <hip/hip_runtime.h>

typedef _Float16 f16x8 __attribute__((ext_vector_type(8)));
typedef _Float16 f16x4 __attribute__((ext_vector_type(4)));
typedef float    f32x4 __attribute__((ext_vector_type(4)));
typedef int      i32x4 __attribute__((ext_vector_type(4)));

#define S_LEN 2048
#define D_KH  64
#define NBH   32                       // B*H
#define QTILE 16
#define NBLK  (NBH * (S_LEN / QTILE))  // 4096
#define THREADS 512                    // 8 waves
#define QK_ELEMS (NBH * S_LEN * D_KH)

__device__ __forceinline__ f16x8 cvt8(const float4 a, const float4 b) {
  f16x8 r;
  r[0] = (_Float16)a.x; r[1] = (_Float16)a.y;
  r[2] = (_Float16)a.z; r[3] = (_Float16)a.w;
  r[4] = (_Float16)b.x; r[5] = (_Float16)b.y;
  r[6] = (_Float16)b.z; r[7] = (_Float16)b.w;
  return r;
}

// Prep: K -> f16, q -> f16 pre-scaled by 1/sqrt(64).
__global__ __launch_bounds__(256) void cvt_qk_kernel(
    const float* __restrict__ q, const float* __restrict__ kmat,
    _Float16* __restrict__ qh, _Float16* __restrict__ kh) {
  const long long idx = ((long long)blockIdx.x * 256 + threadIdx.x) * 8;
  float4 q0 = *(const float4*)(q + idx);
  float4 q1 = *(const float4*)(q + idx + 4);
  const float s = 0.125f;
  q0.x *= s; q0.y *= s; q0.z *= s; q0.w *= s;
  q1.x *= s; q1.y *= s; q1.z *= s; q1.w *= s;
  *(f16x8*)(qh + idx) = cvt8(q0, q1);
  const float4 k0 = *(const float4*)(kmat + idx);
  const float4 k1 = *(const float4*)(kmat + idx + 4);
  *(f16x8*)(kh + idx) = cvt8(k0, k1);
}

template <bool F16>
__global__ __launch_bounds__(THREADS, 4) void sdpa_probs_kernel(
    const float* __restrict__ qf, const float* __restrict__ kf,
    const _Float16* __restrict__ qh, const _Float16* __restrict__ kh,
    const int* __restrict__ mask, float* __restrict__ out) {
  // XCD-aware swizzle: 512 consecutive nb per XCD -> 4 heads' f16 panels hot
  // in one XCD L2.
  const int bid = (int)blockIdx.x;
  const int nb  = (bid & 7) * (NBLK / 8) + (bid >> 3);
  const int bh  = nb >> 7;
  const int qt  = nb & 127;

  __shared__ _Float16 sc[QTILE][S_LEN];  // 64 KiB score strip
  __shared__ float smax[8][QTILE];       // per-wave per-row strip maxes

  const int tid   = (int)threadIdx.x;
  const int w     = tid >> 6;   // wave 0..7
  const int l     = tid & 63;
  const int lo    = l & 15;
  const int g     = l >> 4;
  const int dbase = g << 3;

  const size_t qk_bh = (size_t)bh * S_LEN * D_KH;
  const size_t obh   = (size_t)bh * S_LEN * S_LEN;

  const int rowA = w << 1, rowB = rowA + 1;   // wave w owns rows 2w, 2w+1
  const size_t orowA = obh + (size_t)(qt * QTILE + rowA) * S_LEN;
  const size_t orowB = obh + (size_t)(qt * QTILE + rowB) * S_LEN;

  // ---- Row-A masks upfront: HBM latency/traffic lands under phase 1 ----
  i32x4 mA[8];
  {
    const int* mp = mask + orowA + (l << 2);
    #pragma unroll
    for (int i = 0; i < 8; ++i)
      mA[i] = __builtin_nontemporal_load((const i32x4*)(mp + (i << 8)));
  }

  // ---- A fragments: q rows (pre-scaled) ----
  f16x8 a0, a1;
  if constexpr (F16) {
    const _Float16* qp = qh + qk_bh + (size_t)(qt * QTILE + lo) * D_KH + dbase;
    a0 = *(const f16x8*)qp;
    a1 = *(const f16x8*)(qp + 32);
  } else {
    const float* qp = qf + qk_bh + (size_t)(qt * QTILE + lo) * D_KH;
    float4 t0 = *(const float4*)(qp + dbase);
    float4 t1 = *(const float4*)(qp + dbase + 4);
    float4 t2 = *(const float4*)(qp + dbase + 32);
    float4 t3 = *(const float4*)(qp + dbase + 36);
    const float s = 0.125f;
    t0.x *= s; t0.y *= s; t0.z *= s; t0.w *= s;
    t1.x *= s; t1.y *= s; t1.z *= s; t1.w *= s;
    t2.x *= s; t2.y *= s; t2.z *= s; t2.w *= s;
    t3.x *= s; t3.y *= s; t3.z *= s; t3.w *= s;
    a0 = cvt8(t0, t1);
    a1 = cvt8(t2, t3);
  }

  // ---- Phase 1: scores + ONLINE row-max (raw, pre-mask: softmax is
  //      shift-invariant, any M >= true max is numerically safe).
  f32x4 rm = {-3.0e38f, -3.0e38f, -3.0e38f, -3.0e38f};
  #pragma unroll 4
  for (int kt = 0; kt < 16; ++kt) {
    const int kcol = (w << 8) + (kt << 4) + lo;
    f16x8 b0, b1;
    if constexpr (F16) {
      const _Float16* kp = kh + qk_bh + (size_t)kcol * D_KH + dbase;
      b0 = *(const f16x8*)kp;
      b1 = *(const f16x8*)(kp + 32);
    } else {
      const float* kp = kf + qk_bh + (size_t)kcol * D_KH + dbase;
      b0 = cvt8(*(const float4*)(kp), *(const float4*)(kp + 4));
      b1 = cvt8(*(const float4*)(kp + 32), *(const float4*)(kp + 36));
    }
    f32x4 acc = {0.f, 0.f, 0.f, 0.f};
    acc = __builtin_amdgcn_mfma_f32_16x16x32_f16(a0, b0, acc, 0, 0, 0);
    acc = __builtin_amdgcn_mfma_f32_16x16x32_f16(a1, b1, acc, 0, 0, 0);
    rm[0] = fmaxf(rm[0], acc[0]); rm[1] = fmaxf(rm[1], acc[1]);
    rm[2] = fmaxf(rm[2], acc[2]); rm[3] = fmaxf(rm[3], acc[3]);
    // D layout: row = 4g+r, col = lo. XOR-swizzle col bit4 by g -> 32 banks.
    const int phys = kcol ^ (g << 4);
    #pragma unroll
    for (int r = 0; r < 4; ++r)
      sc[(g << 2) + r][phys] = (_Float16)acc[r];
  }

  // Reduce rm over the 16 lanes of each g-group -> strip max for rows 4g+r.
  #pragma unroll
  for (int c = 0; c < 4; ++c) {
    float v = rm[c];
    v = fmaxf(v, __shfl_xor(v, 1, 64));
    v = fmaxf(v, __shfl_xor(v, 2, 64));
    v = fmaxf(v, __shfl_xor(v, 4, 64));
    v = fmaxf(v, __shfl_xor(v, 8, 64));
    rm[c] = v;
  }
  if (lo == 0) {
    smax[w][(g << 2) + 0] = rm[0];
    smax[w][(g << 2) + 1] = rm[1];
    smax[w][(g << 2) + 2] = rm[2];
    smax[w][(g << 2) + 3] = rm[3];
  }

  #pragma unroll
  for (int i = 0; i < 8; ++i) asm volatile("" :: "v"(mA[i]));
  __syncthreads();

  // ---- Row-B masks now: latency hides under sumA + storeA ----
  i32x4 mB[8];
  {
    const int* mp = mask + orowB + (l << 2);
    #pragma unroll
    for (int i = 0; i < 8; ++i)
      mB[i] = __builtin_nontemporal_load((const i32x4*)(mp + (i << 8)));
  }

  // Global row maxes (8 broadcast LDS reads each).
  float gA = smax[0][rowA], gB = smax[0][rowB];
  #pragma unroll
  for (int j = 1; j < 8; ++j) {
    gA = fmaxf(gA, smax[j][rowA]);
    gB = fmaxf(gB, smax[j][rowB]);
  }

  const int physx = (w >> 1) << 4;   // rowA>>2 == rowB>>2 == w>>1

  // ---- sumA: exp + mask fold, write exp back to LDS (f16) ----
  float sum = 0.f;
  #pragma unroll
  for (int i = 0; i < 8; ++i) {
    const int off = (((i << 8) + (l << 2))) ^ physx;
    const f16x4 h = *(const f16x4*)&sc[rowA][off];
    const float e0 = mA[i].x ? 0.f : __expf((float)h[0] - gA);
    const float e1 = mA[i].y ? 0.f : __expf((float)h[1] - gA);
    const float e2 = mA[i].z ? 0.f : __expf((float)h[2] - gA);
    const float e3 = mA[i].w ? 0.f : __expf((float)h[3] - gA);
    sum += (e0 + e1) + (e2 + e3);
    f16x4 eh; eh[0] = (_Float16)e0; eh[1] = (_Float16)e1;
    eh[2] = (_Float16)e2; eh[3] = (_Float16)e3;
    *(f16x4*)&sc[rowA][off] = eh;
  }
  #pragma unroll
  for (int off = 32; off > 0; off >>= 1)
    sum += __shfl_xor(sum, off, 64);
  const float invA = 1.0f / sum;

  // ---- storeA: read exp'd f16, scale, nontemporal store ----
  float* opA = out + orowA;
  #pragma unroll
  for (int i = 0; i < 8; ++i) {
    const int col = (i << 8) + (l << 2);
    const f16x4 h = *(const f16x4*)&sc[rowA][col ^ physx];
    f32x4 o = { (float)h[0] * invA, (float)h[1] * invA,
                (float)h[2] * invA, (float)h[3] * invA };
    __builtin_nontemporal_store(o, (f32x4*)(opA + col));
  }

  // ---- sumB / storeB ----
  sum = 0.f;
  #pragma unroll
  for (int i = 0; i < 8; ++i) {
    const int off = (((i << 8) + (l << 2))) ^ physx;
    const f16x4 h = *(const f16x4*)&sc[rowB][off];
    const float e0 = mB[i].x ? 0.f : __expf((float)h[0] - gB);
    const float e1 = mB[i].y ? 0.f : __expf((float)h[1] - gB);
    const float e2 = mB[i].z ? 0.f : __expf((float)h[2] - gB);
    const float e3 = mB[i].w ? 0.f : __expf((float)h[3] - gB);
    sum += (e0 + e1) + (e2 + e3);
    f16x4 eh; eh[0] = (_Float16)e0; eh[1] = (_Float16)e1;
    eh[2] = (_Float16)e2; eh[3] = (_Float16)e3;
    *(f16x4*)&sc[rowB][off] = eh;
  }
  #pragma unroll
  for (int off = 32; off > 0; off >>= 1)
    sum += __shfl_xor(sum, off, 64);
  const float invB = 1.0f / sum;

  float* opB = out + orowB;
  #pragma unroll
  for (int i = 0; i < 8; ++i) {
    const int col = (i << 8) + (l << 2);
    const f16x4 h = *(const f16x4*)&sc[rowB][col ^ physx];
    f32x4 o = { (float)h[0] * invB, (float)h[1] * invB,
                (float)h[2] * invB, (float)h[3] * invB };
    __builtin_nontemporal_store(o, (f32x4*)(opB + col));
  }
}

extern "C" void kernel_launch(void* const* d_in, const int* in_sizes, int n_in,
                              void* d_out, int out_size, void* d_ws, size_t ws_size,
                              hipStream_t stream) {
  const float* q    = (const float*)d_in[0];
  const float* kmat = (const float*)d_in[1];
  // d_in[2] = v, unused (reference stops at softmax)
  const int*   mask = (const int*)d_in[3];
  float*       out  = (float*)d_out;

  const size_t need = (size_t)QK_ELEMS * 2 * sizeof(_Float16);
  if (ws_size >= need) {
    _Float16* qh = (_Float16*)d_ws;
    _Float16* kh = qh + QK_ELEMS;
    cvt_qk_kernel<<<dim3(QK_ELEMS / 8 / 256), dim3(256), 0, stream>>>(q, kmat, qh, kh);
    sdpa_probs_kernel<true><<<dim3(NBLK), dim3(THREADS), 0, stream>>>(
        nullptr, nullptr, qh, kh, mask, out);
  } else {
    sdpa_probs_kernel<false><<<dim3(NBLK), dim3(THREADS), 0, stream>>>(
        q, kmat, nullptr, nullptr, mask, out);
  }
}